// Round 2
// baseline (216.657 us; speedup 1.0000x reference)
//
#include <hip/hip_runtime.h>

// Point-splat renderer, round 2:
//   Per-XCD private winner buffers updated with workgroup-scope atomicMax
//   (executes in the local XCD's L2 instead of the memory-side coherence
//   point), plus a monotonicity-based read-precheck to skip losing atomics.
//   Paint pass reduces max over the 8 per-XCD buffers and gathers colors.
//
// Inputs (setup_inputs order):
//   d_in[0] positions (N*3 f32), d_in[1] colors (N*3 f32),
//   d_in[2] camera_pose (16 f32), d_in[3] intrinsics (9 f32),
//   d_in[4] H (1 int), d_in[5] W (1 int)
// Output: (1,3,H,W) f32 flat.

__device__ __forceinline__ unsigned get_xcc_id() {
    unsigned x;
    asm volatile("s_getreg_b32 %0, hwreg(HW_REG_XCC_ID)" : "=s"(x));
    return x & 7u;
}

__global__ void proj_kernel(const float* __restrict__ pos,
                            const float* __restrict__ pose,
                            const float* __restrict__ intr,
                            const int* __restrict__ Hp,
                            const int* __restrict__ Wp,
                            int* __restrict__ winner,
                            int n, int nbuf) {
    int i = blockIdx.x * blockDim.x + threadIdx.x;
    if (i >= n) return;

    float px = pos[3 * i + 0];
    float py = pos[3 * i + 1];
    float pz = pos[3 * i + 2];

    // pc = R * p + t
    float x = pose[0] * px + pose[1] * py + pose[2]  * pz + pose[3];
    float y = pose[4] * px + pose[5] * py + pose[6]  * pz + pose[7];
    float z = pose[8] * px + pose[9] * py + pose[10] * pz + pose[11];

    float fx = intr[0], cx = intr[2];
    float fy = intr[4], cy = intr[5];

    float u = fx * x / z + cx;
    float v = fy * y / z + cy;

    int xi = (int)u;   // trunc toward zero == numpy astype(int32)
    int yi = (int)v;

    int W = *Wp, H = *Hp;
    if (xi >= 0 && xi < W && yi >= 0 && yi < H) {
        int pix = yi * W + xi;
        if (nbuf == 8) {
            // XCD-private buffer: all writers of this buffer share one L2,
            // so workgroup-scope (L2-point) atomicity is sufficient.
            int* buf = winner + (size_t)get_xcc_id() * (size_t)(W * H);
            if (buf[pix] < i) {   // stale read is <= true value (monotone) -> safe skip
                __hip_atomic_fetch_max(buf + pix, i, __ATOMIC_RELAXED,
                                       __HIP_MEMORY_SCOPE_WORKGROUP);
            }
        } else {
            if (winner[pix] < i) {
                atomicMax(&winner[pix], i);   // agent scope fallback
            }
        }
    }
}

__global__ void paint_kernel(const int* __restrict__ winner,
                             const float* __restrict__ colors,
                             float* __restrict__ out,
                             int HW, int nbuf) {
    int p = blockIdx.x * blockDim.x + threadIdx.x;
    if (p >= HW) return;

    int w = winner[p];
    #pragma unroll
    for (int k = 1; k < 8; ++k) {
        if (k < nbuf) w = max(w, winner[(size_t)k * HW + p]);
    }

    float r = 0.0f, g = 0.0f, b = 0.0f;
    if (w >= 0) {
        r = colors[3 * w + 0];
        g = colors[3 * w + 1];
        b = colors[3 * w + 2];
        r = fminf(fmaxf(r, 0.0f), 1.0f);
        g = fminf(fmaxf(g, 0.0f), 1.0f);
        b = fminf(fmaxf(b, 0.0f), 1.0f);
    }
    out[p] = r;
    out[HW + p] = g;
    out[2 * HW + p] = b;
}

extern "C" void kernel_launch(void* const* d_in, const int* in_sizes, int n_in,
                              void* d_out, int out_size, void* d_ws, size_t ws_size,
                              hipStream_t stream) {
    const float* positions = (const float*)d_in[0];
    const float* colors    = (const float*)d_in[1];
    const float* pose      = (const float*)d_in[2];
    const float* intr      = (const float*)d_in[3];
    const int*   Hp        = (const int*)d_in[4];
    const int*   Wp        = (const int*)d_in[5];
    float* out = (float*)d_out;

    int n  = in_sizes[0] / 3;       // number of points
    int HW = out_size / 3;          // H*W pixels

    int* winner = (int*)d_ws;
    size_t need8 = (size_t)8 * (size_t)HW * sizeof(int);
    int nbuf = (ws_size >= need8) ? 8 : 1;

    // winner = -1 everywhere (0xFF bytes)
    hipMemsetAsync(winner, 0xFF, (size_t)nbuf * (size_t)HW * sizeof(int), stream);

    int block = 256;
    int grid1 = (n + block - 1) / block;
    proj_kernel<<<grid1, block, 0, stream>>>(positions, pose, intr, Hp, Wp,
                                             winner, n, nbuf);

    int grid2 = (HW + block - 1) / block;
    paint_kernel<<<grid2, block, 0, stream>>>(winner, colors, out, HW, nbuf);
}

// Round 3
// 182.714 us; speedup vs baseline: 1.1858x; 1.1858x over previous
//
#include <hip/hip_runtime.h>
#include <stdint.h>

// Point-splat renderer, round 3:
//   Per-XCD private winner buffers + inline-asm `global_atomic_smax` WITHOUT
//   sc1, so the RMW executes in the local XCD's L2 (line stays dirty in TCC)
//   instead of write-through at the memory-side coherence point (round 1/2:
//   WRITE_SIZE == 4M x 32B == per-atomic write-through).
//   Safety: all writers of one buffer share that L2 (HW_REG_XCC_ID selects),
//   and end-of-dispatch release writes dirty lines back before paint runs.
//
// Inputs: d_in[0] positions (N*3 f32), d_in[1] colors (N*3 f32),
//         d_in[2] camera_pose (16 f32), d_in[3] intrinsics (9 f32),
//         d_in[4] H (1 int), d_in[5] W (1 int)
// Output: (1,3,H,W) f32 flat.

__device__ __forceinline__ unsigned get_xcc_id() {
    unsigned x;
    asm volatile("s_getreg_b32 %0, hwreg(HW_REG_XCC_ID)" : "=s"(x));
    return x & 7u;
}

__global__ void proj_kernel(const float* __restrict__ pos,
                            const float* __restrict__ pose,
                            const float* __restrict__ intr,
                            const int* __restrict__ Hp,
                            const int* __restrict__ Wp,
                            int* __restrict__ winner,
                            int n, int nbuf) {
    int i = blockIdx.x * blockDim.x + threadIdx.x;
    if (i < n) {
        float px = pos[3 * i + 0];
        float py = pos[3 * i + 1];
        float pz = pos[3 * i + 2];

        // pc = R * p + t
        float x = pose[0] * px + pose[1] * py + pose[2]  * pz + pose[3];
        float y = pose[4] * px + pose[5] * py + pose[6]  * pz + pose[7];
        float z = pose[8] * px + pose[9] * py + pose[10] * pz + pose[11];

        float fx = intr[0], cx = intr[2];
        float fy = intr[4], cy = intr[5];

        float u = fx * x / z + cx;
        float v = fy * y / z + cy;

        int xi = (int)u;   // trunc toward zero == numpy astype(int32)
        int yi = (int)v;

        int W = *Wp, H = *Hp;
        if (xi >= 0 && xi < W && yi >= 0 && yi < H) {
            int pix = yi * W + xi;
            if (nbuf == 8) {
                // XCD-private buffer; flagless atomic -> RMW executes in the
                // local TCC (L2), no per-op HBM write-through.
                int* p = winner + (size_t)get_xcc_id() * (size_t)(W * H) + pix;
                asm volatile("global_atomic_smax %0, %1, off"
                             :: "v"(p), "v"(i) : "memory");
            } else {
                atomicMax(&winner[pix], i);   // device-scope fallback
            }
        }
    }
    // Drain the fire-and-forget asm atomic before wave exit.
    asm volatile("s_waitcnt vmcnt(0)" ::: "memory");
}

__global__ void paint_kernel(const int* __restrict__ winner,
                             const float* __restrict__ colors,
                             float* __restrict__ out,
                             int HW, int nbuf) {
    int p = blockIdx.x * blockDim.x + threadIdx.x;
    if (p >= HW) return;

    int w = winner[p];
    #pragma unroll
    for (int k = 1; k < 8; ++k) {
        if (k < nbuf) w = max(w, winner[(size_t)k * HW + p]);
    }

    float r = 0.0f, g = 0.0f, b = 0.0f;
    if (w >= 0) {
        r = colors[3 * w + 0];
        g = colors[3 * w + 1];
        b = colors[3 * w + 2];
        r = fminf(fmaxf(r, 0.0f), 1.0f);
        g = fminf(fmaxf(g, 0.0f), 1.0f);
        b = fminf(fmaxf(b, 0.0f), 1.0f);
    }
    out[p] = r;
    out[HW + p] = g;
    out[2 * HW + p] = b;
}

extern "C" void kernel_launch(void* const* d_in, const int* in_sizes, int n_in,
                              void* d_out, int out_size, void* d_ws, size_t ws_size,
                              hipStream_t stream) {
    const float* positions = (const float*)d_in[0];
    const float* colors    = (const float*)d_in[1];
    const float* pose      = (const float*)d_in[2];
    const float* intr      = (const float*)d_in[3];
    const int*   Hp        = (const int*)d_in[4];
    const int*   Wp        = (const int*)d_in[5];
    float* out = (float*)d_out;

    int n  = in_sizes[0] / 3;       // number of points
    int HW = out_size / 3;          // H*W pixels

    int* winner = (int*)d_ws;
    size_t need8 = (size_t)8 * (size_t)HW * sizeof(int);
    int nbuf = (ws_size >= need8) ? 8 : 1;

    // winner = -1 everywhere (0xFF bytes)
    hipMemsetAsync(winner, 0xFF, (size_t)nbuf * (size_t)HW * sizeof(int), stream);

    int block = 256;
    int grid1 = (n + block - 1) / block;
    proj_kernel<<<grid1, block, 0, stream>>>(positions, pose, intr, Hp, Wp,
                                             winner, n, nbuf);

    int grid2 = (HW + block - 1) / block;
    paint_kernel<<<grid2, block, 0, stream>>>(winner, colors, out, HW, nbuf);
}

// Round 4
// 97.645 us; speedup vs baseline: 2.2188x; 1.8712x over previous
//
#include <hip/hip_runtime.h>

// Point-splat renderer, round 4: descending-chunk atomics + coverage bitmask.
//
// winner[pix] = max point index hitting pix. Key fact: after processing the
// index chunk [a,b), any pixel with winner>=0 has winner>=a, which beats every
// remaining (lower) index -> record coverage in a 1-bit/pixel mask (128 KB,
// read-only during the next pass, L1/L2 resident) and skip the memory-side
// atomic RMW (measured cost: 32 B HBM-side write per op, the 152 us limiter
// of rounds 1-3). Expected atomic count drops 4M -> ~0.85M.
//
// Inputs: d_in[0] positions (N*3 f32), d_in[1] colors (N*3 f32),
//         d_in[2] camera_pose (16 f32), d_in[3] intrinsics (9 f32),
//         d_in[4] H (1 int), d_in[5] W (1 int)
// Output: (1,3,H,W) f32 flat.

__global__ void proj_kernel(const float* __restrict__ pos,
                            const float* __restrict__ pose,
                            const float* __restrict__ intr,
                            const int* __restrict__ Hp,
                            const int* __restrict__ Wp,
                            int* __restrict__ winner,
                            const unsigned* __restrict__ mask,
                            int use_mask, int start, int end) {
    int i = start + blockIdx.x * blockDim.x + threadIdx.x;
    if (i >= end) return;

    float px = pos[3 * i + 0];
    float py = pos[3 * i + 1];
    float pz = pos[3 * i + 2];

    // pc = R * p + t
    float x = pose[0] * px + pose[1] * py + pose[2]  * pz + pose[3];
    float y = pose[4] * px + pose[5] * py + pose[6]  * pz + pose[7];
    float z = pose[8] * px + pose[9] * py + pose[10] * pz + pose[11];

    float fx = intr[0], cx = intr[2];
    float fy = intr[4], cy = intr[5];

    float u = fx * x / z + cx;
    float v = fy * y / z + cy;

    int xi = (int)u;   // trunc toward zero == numpy astype(int32)
    int yi = (int)v;

    int W = *Wp, H = *Hp;
    if (xi >= 0 && xi < W && yi >= 0 && yi < H) {
        int pix = yi * W + xi;
        if (use_mask && ((mask[pix >> 5] >> (pix & 31)) & 1u)) return; // settled
        atomicMax(&winner[pix], i);
    }
}

// covered-bitmask: bit p = (winner[p] >= 0). Full overwrite each call.
__global__ void mask_kernel(const int* __restrict__ winner,
                            unsigned* __restrict__ mask,
                            int HW, int maskWords) {
    int p = blockIdx.x * blockDim.x + threadIdx.x;
    bool pred = (p < HW) && (winner[p] >= 0);
    unsigned long long b = __ballot(pred);
    int lane = threadIdx.x & 63;
    if (lane == 0) {
        int base = (blockIdx.x * blockDim.x + (threadIdx.x & ~63)) >> 5;
        if (base < maskWords)     mask[base]     = (unsigned)b;
        if (base + 1 < maskWords) mask[base + 1] = (unsigned)(b >> 32);
    }
}

__global__ void paint_kernel(const int* __restrict__ winner,
                             const float* __restrict__ colors,
                             float* __restrict__ out,
                             int HW) {
    int p = blockIdx.x * blockDim.x + threadIdx.x;
    if (p >= HW) return;

    int w = winner[p];
    float r = 0.0f, g = 0.0f, b = 0.0f;
    if (w >= 0) {
        r = colors[3 * w + 0];
        g = colors[3 * w + 1];
        b = colors[3 * w + 2];
        r = fminf(fmaxf(r, 0.0f), 1.0f);
        g = fminf(fmaxf(g, 0.0f), 1.0f);
        b = fminf(fmaxf(b, 0.0f), 1.0f);
    }
    out[p] = r;
    out[HW + p] = g;
    out[2 * HW + p] = b;
}

extern "C" void kernel_launch(void* const* d_in, const int* in_sizes, int n_in,
                              void* d_out, int out_size, void* d_ws, size_t ws_size,
                              hipStream_t stream) {
    const float* positions = (const float*)d_in[0];
    const float* colors    = (const float*)d_in[1];
    const float* pose      = (const float*)d_in[2];
    const float* intr      = (const float*)d_in[3];
    const int*   Hp        = (const int*)d_in[4];
    const int*   Wp        = (const int*)d_in[5];
    float* out = (float*)d_out;

    int n  = in_sizes[0] / 3;       // number of points
    int HW = out_size / 3;          // H*W pixels

    int* winner = (int*)d_ws;
    int maskWords = (HW + 31) / 32;
    unsigned* mask = (unsigned*)((char*)d_ws + (size_t)HW * sizeof(int));
    size_t need = (size_t)HW * sizeof(int) + (size_t)maskWords * sizeof(unsigned);

    const int block = 256;

    // winner = -1 everywhere (0xFF bytes)
    hipMemsetAsync(winner, 0xFF, (size_t)HW * sizeof(int), stream);

    if (ws_size < need || n < 1024) {
        // Fallback: single full pass, no mask.
        int grid = (n + block - 1) / block;
        proj_kernel<<<grid, block, 0, stream>>>(positions, pose, intr, Hp, Wp,
                                                winner, (const unsigned*)0, 0, 0, n);
    } else {
        // Descending index chunks; rebuild coverage mask between chunks.
        long long ln = n;
        int bounds[6];
        bounds[0] = n;
        bounds[1] = (int)(ln * 7 / 8);
        bounds[2] = (int)(ln * 3 / 4);
        bounds[3] = (int)(ln * 5 / 8);
        bounds[4] = (int)(ln / 2);
        bounds[5] = 0;

        int maskGrid = (HW + block - 1) / block;
        for (int k = 0; k < 5; ++k) {
            int end = bounds[k], start = bounds[k + 1];
            int cnt = end - start;
            if (cnt <= 0) continue;
            int grid = (cnt + block - 1) / block;
            proj_kernel<<<grid, block, 0, stream>>>(positions, pose, intr, Hp, Wp,
                                                    winner, mask, (k > 0) ? 1 : 0,
                                                    start, end);
            if (k < 4) {
                mask_kernel<<<maskGrid, block, 0, stream>>>(winner, mask, HW, maskWords);
            }
        }
    }

    int grid2 = (HW + block - 1) / block;
    paint_kernel<<<grid2, block, 0, stream>>>(winner, colors, out, HW);
}